// Round 2
// 828.963 us; speedup vs baseline: 1.1559x; 1.1559x over previous
//
#include <hip/hip_runtime.h>
#include <cstdint>
#include <cstddef>

typedef __attribute__((ext_vector_type(8))) short short8;
typedef __attribute__((ext_vector_type(4))) short short4v;
typedef __attribute__((ext_vector_type(4))) float float4v;
typedef __attribute__((ext_vector_type(4))) int int4v;
typedef unsigned short ushort_t;

__device__ __forceinline__ ushort_t f2bf(float f) {
  unsigned u = __builtin_bit_cast(unsigned, f);
  u = (u + 0x7FFFu + ((u >> 16) & 1u)) >> 16;  // RNE
  return (ushort_t)u;
}
__device__ __forceinline__ float bf2f(ushort_t h) {
  unsigned u = ((unsigned)h) << 16;
  return __builtin_bit_cast(float, u);
}

__device__ __forceinline__ void gld_lds16(const void* g, void* l) {
  __builtin_amdgcn_global_load_lds(
      (const __attribute__((address_space(1))) void*)g,
      (__attribute__((address_space(3))) void*)l, 16, 0, 0);
}

// ---------------------------------------------------------------------------
// TN GEMM, plain-store split-K: P[z][m][n] = sum_{k in slice z} A[m][k]*B[n][k]
// A:[M][K] bf16, B:[N][K] bf16. Tile 128x128, BK=64.
// K=8192 -> 128 k-tiles split over 12 z-slices as 8x11 + 4x10.
// grid (M/128, N/128, 12), block 256 (4 waves, 2x2 of 64x64).
// ---------------------------------------------------------------------------
__global__ __launch_bounds__(256, 3) void gemm_tn(
    const ushort_t* __restrict__ A, const ushort_t* __restrict__ B,
    float* __restrict__ P, int M, int N, int K) {
  __shared__ ushort_t As[128 * 64];
  __shared__ ushort_t Bs[128 * 64];
  const int tid = threadIdx.x;
  const int lane = tid & 63;
  const int wave = tid >> 6;
  const int wm = (wave & 1) * 64;
  const int wn = (wave >> 1) * 64;
  const int m0 = blockIdx.x * 128;
  const int n0 = blockIdx.y * 128;
  int t0, tl;
  if (blockIdx.z < 8) { t0 = blockIdx.z * 11; tl = 11; }
  else { t0 = 88 + (blockIdx.z - 8) * 10; tl = 10; }
  float* __restrict__ Pc = P + (size_t)blockIdx.z * M * N;

  float4v acc[4][4] = {};

  for (int t = t0; t < t0 + tl; t++) {
    const ushort_t* Ag = A + (size_t)m0 * K + t * 64;
    const ushort_t* Bg = B + (size_t)n0 * K + t * 64;
#pragma unroll
    for (int i = 0; i < 4; i++) {
      int f = i * 4096 + tid * 16;  // flat byte in 16KB tile
      int r = f >> 7;               // row (128B per row = 64 bf16)
      int cb = f & 127;             // byte within row
      gld_lds16((const char*)(Ag + (size_t)r * K) + cb, (char*)As + f);
      gld_lds16((const char*)(Bg + (size_t)r * K) + cb, (char*)Bs + f);
    }
    __syncthreads();
#pragma unroll
    for (int ks = 0; ks < 64; ks += 32) {
      short8 af[4], bfr[4];
      const int kr = ks + (lane >> 4) * 8;
      const int l15 = lane & 15;
#pragma unroll
      for (int im = 0; im < 4; im++)
        af[im] = *(const short8*)&As[(wm + im * 16 + l15) * 64 + kr];
#pragma unroll
      for (int in = 0; in < 4; in++)
        bfr[in] = *(const short8*)&Bs[(wn + in * 16 + l15) * 64 + kr];
#pragma unroll
      for (int im = 0; im < 4; im++)
#pragma unroll
        for (int in = 0; in < 4; in++)
          acc[im][in] = __builtin_amdgcn_mfma_f32_16x16x32_bf16(
              af[im], bfr[in], acc[im][in], 0, 0, 0);
    }
    __syncthreads();
  }
  // C/D layout: col(n) = lane&15, row(m) = (lane>>4)*4 + reg  [m89/m91]
  const int cn = lane & 15;
  const int cr = (lane >> 4) * 4;
#pragma unroll
  for (int im = 0; im < 4; im++)
#pragma unroll
    for (int in = 0; in < 4; in++)
#pragma unroll
      for (int r = 0; r < 4; r++) {
        int m = wm + im * 16 + cr + r;
        int n = wn + in * 16 + cn;
        Pc[(size_t)(m0 + m) * N + (n0 + n)] = acc[im][in][r];
      }
}

// ---------------------------------------------------------------------------
// NN GEMM, plain-store split-K: P[z][m][n] = sum_{k in slice z} A[m][k]*B[k][n]
// A:[M][K] bf16 (K-contig), B:[K][N] bf16 row-major (read directly, no
// transposed copy). B-tile staged into LDS as 128B granules of [4 k][16 n]
// (granule index g = k4*8 + cq, k4-major) so global_load_lds sources stay
// coalesced. B MFMA fragments gathered with ds_read_b64_tr_b16.
// tr-read address encoding [m156/m162]: delivered byte j =
//   (a & ~127) + ((a>>3)&15)*2 + j*32
// i.e. addr bits [6:3] select the granule COLUMN -> column c needs +c*8
// bytes of address (NOT +c*2 — that was round-0's bug).
// ---------------------------------------------------------------------------
__global__ __launch_bounds__(256, 3) void gemm_nn(
    const ushort_t* __restrict__ A, const ushort_t* __restrict__ B,
    float* __restrict__ P, int M, int N, int K) {
  __shared__ ushort_t As[128 * 64];
  __shared__ ushort_t Bs[64 * 128];
  const int tid = threadIdx.x;
  const int lane = tid & 63;
  const int wave = tid >> 6;
  const int wm = (wave & 1) * 64;
  const int wn = (wave >> 1) * 64;
  const int m0 = blockIdx.x * 128;
  const int n0 = blockIdx.y * 128;
  int t0, tl;
  if (blockIdx.z < 8) { t0 = blockIdx.z * 11; tl = 11; }
  else { t0 = 88 + (blockIdx.z - 8) * 10; tl = 10; }
  float* __restrict__ Pc = P + (size_t)blockIdx.z * M * N;

  // B-staging map (loop-invariant): 16B chunk c -> (k row, col) of the tile.
  // LDS byte x=c*16: granule g=c>>3 (=k4*8+cq), krow=(c>>1)&3, half=c&1.
  int brow[4], bcol[4];
#pragma unroll
  for (int i = 0; i < 4; i++) {
    const int c = i * 256 + tid;
    brow[i] = ((c >> 6) << 2) | ((c >> 1) & 3);          // k4*4 + krow
    bcol[i] = (((c >> 3) & 7) << 4) | ((c & 1) << 3);    // cq*16 + half*8
  }
  const int l15 = lane & 15;
  const int hi = lane >> 4;
  const unsigned BsB =
      (unsigned)(uintptr_t)(__attribute__((address_space(3))) void*)Bs;
  // frag k = ks + 8*hi + j  -> granule k4 = ks/4 + 2*hi (r0), +1 (r1)
  // column select l15 -> +l15*8 address bytes (bits [6:3])
  const unsigned trb = BsB + (unsigned)(hi * 2048) + (unsigned)(l15 * 8);

  float4v acc[4][4] = {};

  for (int t = t0; t < t0 + tl; t++) {
    const ushort_t* Ag = A + (size_t)m0 * K + t * 64;
    const ushort_t* Bg = B + (size_t)(t * 64) * N + n0;
#pragma unroll
    for (int i = 0; i < 4; i++) {
      int f = i * 4096 + tid * 16;
      int r = f >> 7;
      int cb = f & 127;
      gld_lds16((const char*)(Ag + (size_t)r * K) + cb, (char*)As + f);
      gld_lds16((const char*)(Bg + (size_t)brow[i] * N + bcol[i]),
                (char*)Bs + f);
    }
    __syncthreads();
#pragma unroll
    for (int ks = 0; ks < 64; ks += 32) {
      short8 af[4];
      const int kr = ks + hi * 8;
#pragma unroll
      for (int im = 0; im < 4; im++)
        af[im] = *(const short8*)&As[(wm + im * 16 + l15) * 64 + kr];
      short4v r0[4], r1[4];
      const unsigned tb = trb + (unsigned)((ks >> 2) * 1024) + (unsigned)(wn * 8);
#pragma unroll
      for (int in = 0; in < 4; in++) {
        asm volatile(
            "ds_read_b64_tr_b16 %0, %2\n\t"
            "ds_read_b64_tr_b16 %1, %2 offset:1024"
            : "=&v"(r0[in]), "=&v"(r1[in])
            : "v"(tb + (unsigned)(in * 128)));
      }
      asm volatile("s_waitcnt lgkmcnt(0)" ::: "memory");
      __builtin_amdgcn_sched_barrier(0);
#pragma unroll
      for (int im = 0; im < 4; im++)
#pragma unroll
        for (int in = 0; in < 4; in++) {
          short8 bf8 = __builtin_shufflevector(r0[in], r1[in],
                                               0, 1, 2, 3, 4, 5, 6, 7);
          acc[im][in] = __builtin_amdgcn_mfma_f32_16x16x32_bf16(
              af[im], bf8, acc[im][in], 0, 0, 0);
        }
    }
    __syncthreads();
  }
  const int cn = lane & 15;
  const int cr = (lane >> 4) * 4;
#pragma unroll
  for (int im = 0; im < 4; im++)
#pragma unroll
    for (int in = 0; in < 4; in++)
#pragma unroll
      for (int r = 0; r < 4; r++) {
        int m = wm + im * 16 + cr + r;
        int n = wn + in * 16 + cn;
        Pc[(size_t)(m0 + m) * N + (n0 + n)] = acc[im][in][r];
      }
}

// ---------------------------------------------------------------------------
// plain streaming fp32 -> bf16 cast (no transpose), 8 elems/thread
// ---------------------------------------------------------------------------
__global__ __launch_bounds__(256) void cast32_k(
    const float* __restrict__ src, ushort_t* __restrict__ dst) {
  const size_t i = ((size_t)blockIdx.x * 256 + threadIdx.x) * 8;
  float4v a = *(const float4v*)(src + i);
  float4v b = *(const float4v*)(src + i + 4);
  ushort_t o[8];
  o[0] = f2bf(a.x); o[1] = f2bf(a.y); o[2] = f2bf(a.z); o[3] = f2bf(a.w);
  o[4] = f2bf(b.x); o[5] = f2bf(b.y); o[6] = f2bf(b.z); o[7] = f2bf(b.w);
  *(short8*)&dst[i] = *(const short8*)o;
}

// ---------------------------------------------------------------------------
// fp32 [R][C] -> bf16 transposed [C][R] (+ optional non-transposed copy).
// grid.x = COLUMN tile; fp32 LDS tile stride 65: all accesses <=2-way.
// ---------------------------------------------------------------------------
__global__ __launch_bounds__(256) void dualcast_f32_k(
    const float* __restrict__ src, ushort_t* __restrict__ dstN,
    ushort_t* __restrict__ dstT, int R, int C) {
  __shared__ float tile[64][65];
  const int c0 = blockIdx.x * 64, r0 = blockIdx.y * 64;
  const int tr = threadIdx.x >> 2, cs = (threadIdx.x & 3) * 16;
  const float* s = src + (size_t)(r0 + tr) * C + c0 + cs;
  float v[16];
#pragma unroll
  for (int j = 0; j < 16; j += 4) {
    float4v t4 = *(const float4v*)(s + j);
    v[j] = t4.x; v[j + 1] = t4.y; v[j + 2] = t4.z; v[j + 3] = t4.w;
  }
  if (dstN) {
    ushort_t o[16];
#pragma unroll
    for (int j = 0; j < 16; j++) o[j] = f2bf(v[j]);
    ushort_t* d = dstN + (size_t)(r0 + tr) * C + c0 + cs;
    *(short8*)d = *(const short8*)&o[0];
    *(short8*)(d + 8) = *(const short8*)&o[8];
  }
#pragma unroll
  for (int j = 0; j < 16; j++) tile[tr][cs + j] = v[j];
  __syncthreads();
  const int tc = threadIdx.x >> 2, rs = (threadIdx.x & 3) * 16;
  ushort_t o[16];
#pragma unroll
  for (int j = 0; j < 16; j++) o[j] = f2bf(tile[rs + j][tc]);
  ushort_t* d = dstT + (size_t)(c0 + tc) * R + r0 + rs;
  *(short8*)d = *(const short8*)&o[0];
  *(short8*)(d + 8) = *(const short8*)&o[8];
}

// int32 [R][C] -> bf16 (x>0 ? 1 : 0) transposed [C][R]; grid.x = column tile.
// Also emits per-block column partial sums (hyperedge counts) so the old
// 64 MiB hT re-read in counts_k is gone.
__global__ __launch_bounds__(256) void tcast_i32_k(
    const int* __restrict__ src, ushort_t* __restrict__ dstT,
    float* __restrict__ partial, int R, int C) {
  __shared__ float tile[64][65];
  const int c0 = blockIdx.x * 64, r0 = blockIdx.y * 64;
  const int tr = threadIdx.x >> 2, cs = (threadIdx.x & 3) * 16;
  const int* s = src + (size_t)(r0 + tr) * C + c0 + cs;
#pragma unroll
  for (int j = 0; j < 16; j += 4) {
    int4v t4 = *(const int4v*)(s + j);
    tile[tr][cs + j] = t4.x > 0 ? 1.f : 0.f;
    tile[tr][cs + j + 1] = t4.y > 0 ? 1.f : 0.f;
    tile[tr][cs + j + 2] = t4.z > 0 ? 1.f : 0.f;
    tile[tr][cs + j + 3] = t4.w > 0 ? 1.f : 0.f;
  }
  __syncthreads();
  const int tc = threadIdx.x >> 2, rs = (threadIdx.x & 3) * 16;
  ushort_t o[16];
#pragma unroll
  for (int j = 0; j < 16; j++) o[j] = f2bf(tile[rs + j][tc]);
  ushort_t* d = dstT + (size_t)(c0 + tc) * R + r0 + rs;
  *(short8*)d = *(const short8*)&o[0];
  *(short8*)(d + 8) = *(const short8*)&o[8];
  if (threadIdx.x < 64) {
    float sum = 0.f;
#pragma unroll
    for (int r = 0; r < 64; r++) sum += tile[r][threadIdx.x];
    partial[(size_t)(r0 >> 6) * C + c0 + threadIdx.x] = sum;
  }
}

// counts[e] = sum over 128 row-tiles of partial[rt][e]
__global__ __launch_bounds__(256) void counts2_k(
    const float* __restrict__ partial, float* __restrict__ counts, int E) {
  const int e = blockIdx.x * 256 + threadIdx.x;
  float s = 0.f;
  for (int r = 0; r < 128; r++) s += partial[(size_t)r * E + e];
  counts[e] = s;
}

// out_bf16[i] = bf16( sum_s P[s][i] ), S=12 slices
__global__ __launch_bounds__(256) void cast_k(
    const float* __restrict__ P, ushort_t* __restrict__ out, int MN) {
  const int i = (blockIdx.x * 256 + threadIdx.x) * 8;
  float4v a = {0.f, 0.f, 0.f, 0.f}, b = {0.f, 0.f, 0.f, 0.f};
  for (int sp = 0; sp < 12; sp++) {
    a += *(const float4v*)&P[(size_t)sp * MN + i];
    b += *(const float4v*)&P[(size_t)sp * MN + i + 4];
  }
  ushort_t o[8];
  o[0] = f2bf(a.x); o[1] = f2bf(a.y); o[2] = f2bf(a.z); o[3] = f2bf(a.w);
  o[4] = f2bf(b.x); o[5] = f2bf(b.y); o[6] = f2bf(b.z); o[7] = f2bf(b.w);
  *(short8*)&out[i] = *(const short8*)o;
}

// P[s][d][m]: sum 12 slices, LayerNorm over d per column m, write xT[d][m] bf16.
__global__ __launch_bounds__(256) void ln_cast_k(
    const float* __restrict__ P, const float* __restrict__ gamma,
    const float* __restrict__ beta, ushort_t* __restrict__ xT, int Ncols) {
  __shared__ float ssum[8][32], ssq[8][32];
  const int c = threadIdx.x & 31;
  const int q = threadIdx.x >> 5;
  const int m = blockIdx.x * 32 + c;
  const size_t DN = (size_t)128 * Ncols;
  float vloc[16];
  float s = 0.f, sq = 0.f;
#pragma unroll
  for (int j = 0; j < 16; j++) {
    const int d = q * 16 + j;
    float v = 0.f;
    for (int sp = 0; sp < 12; sp++)
      v += P[(size_t)sp * DN + (size_t)d * Ncols + m];
    vloc[j] = v; s += v; sq += v * v;
  }
  ssum[q][c] = s;
  ssq[q][c] = sq;
  __syncthreads();
  float S = 0.f, SQ = 0.f;
#pragma unroll
  for (int r = 0; r < 8; r++) { S += ssum[r][c]; SQ += ssq[r][c]; }
  const float mean = S * (1.f / 128.f);
  const float var = SQ * (1.f / 128.f) - mean * mean;
  const float inv = rsqrtf(var + 1e-5f);
#pragma unroll
  for (int j = 0; j < 16; j++) {
    const int d = q * 16 + j;
    xT[(size_t)d * Ncols + m] = f2bf((vloc[j] - mean) * inv * gamma[d] + beta[d]);
  }
}

// P[s][e][128]: sum 12 slices, divide by counts[e], partial max over 16 e/block
__global__ __launch_bounds__(256) void mm1_k(
    const float* __restrict__ P, const float* __restrict__ counts,
    float* __restrict__ pm, int EMN) {
  __shared__ float4v red[8][32];
  const int el = threadIdx.x >> 5;
  const int l32 = threadIdx.x & 31;
  const int e0 = blockIdx.x * 16;
  float4v vmax = {-3.4e38f, -3.4e38f, -3.4e38f, -3.4e38f};
  for (int ee = el; ee < 16; ee += 8) {
    const int e = e0 + ee;
    float4v s = {0.f, 0.f, 0.f, 0.f};
    for (int sp = 0; sp < 12; sp++)
      s += *(const float4v*)&P[(size_t)sp * EMN + (size_t)e * 128 + l32 * 4];
    const float inv = 1.f / counts[e];
    s *= inv;
    vmax.x = fmaxf(vmax.x, s.x); vmax.y = fmaxf(vmax.y, s.y);
    vmax.z = fmaxf(vmax.z, s.z); vmax.w = fmaxf(vmax.w, s.w);
  }
  red[el][l32] = vmax;
  __syncthreads();
  if (el == 0) {
    float4v m = red[0][l32];
#pragma unroll
    for (int r = 1; r < 8; r++) {
      float4v t = red[r][l32];
      m.x = fmaxf(m.x, t.x); m.y = fmaxf(m.y, t.y);
      m.z = fmaxf(m.z, t.z); m.w = fmaxf(m.w, t.w);
    }
    *(float4v*)&pm[(size_t)blockIdx.x * 128 + l32 * 4] = m;
  }
}

__global__ __launch_bounds__(128) void mm2_k(
    const float* __restrict__ pm, float* __restrict__ out, int B) {
  const int d = threadIdx.x;
  float v = -3.4e38f;
  for (int b = 0; b < B; b++) v = fmaxf(v, pm[b * 128 + d]);
  out[d] = v;
}

// ---------------------------------------------------------------------------
extern "C" void kernel_launch(void* const* d_in, const int* in_sizes, int n_in,
                              void* d_out, int out_size, void* d_ws,
                              size_t ws_size, hipStream_t stream) {
  const float* x0 = (const float*)d_in[0];
  const float* T = (const float*)d_in[1];
  const float* gamma = (const float*)d_in[2];
  const float* beta = (const float*)d_in[3];
  const int* h = (const int*)d_in[4];
  float* out = (float*)d_out;

  const int N = 8192, E = 4096, D = 128, K = 8192, S = 12;

  char* ws = (char*)d_ws;
  size_t off = 0;
  auto alloc = [&](size_t bytes) {
    char* p = ws + off;
    off += (bytes + 255) & ~(size_t)255;
    return p;
  };
  ushort_t* Tb = (ushort_t*)alloc((size_t)N * N * 2);  // T bf16 (single copy)
  ushort_t* hT = (ushort_t*)alloc((size_t)E * N * 2);  // h^T bf16
  ushort_t* xT = (ushort_t*)alloc((size_t)D * N * 2);  // x^T bf16 [128][8192]
  ushort_t* tT = (ushort_t*)alloc((size_t)D * N * 2);  // t^T bf16 [128][8192]
  float* P = (float*)alloc((size_t)S * D * N * 4);     // split-K partials 48MB
  float* counts = (float*)alloc((size_t)E * 4);
  float* partial = (float*)alloc((size_t)(N / 64) * E * 4);  // 2MB count partials
  float* pm = (float*)alloc((size_t)256 * D * 4);
  (void)ws_size;

  // T -> bf16 (no transposed copy: gemm_nn reads Tb directly)
  cast32_k<<<(int)((size_t)N * N / 2048), 256, 0, stream>>>(T, Tb);
  dualcast_f32_k<<<dim3(D / 64, N / 64), 256, 0, stream>>>(x0, nullptr, xT, N, D);
  tcast_i32_k<<<dim3(E / 64, N / 64), 256, 0, stream>>>(h, hT, partial, N, E);
  counts2_k<<<E / 256, 256, 0, stream>>>(partial, counts, E);

  for (int layer = 0; layer < 3; layer++) {
    // tT[d][n] = sum_k xT[d][k] * Tb[n][k]   (t = T x, transposed space, TN)
    gemm_tn<<<dim3(1, N / 128, S), 256, 0, stream>>>(xT, Tb, P, D, N, K);
    cast_k<<<D * N / (256 * 8), 256, 0, stream>>>(P, tT, D * N);
    // x'T[d][m] = sum_k tT[d][k] * Tb[k][m]  (x' = T^T t, NN: reads Tb rows)
    gemm_nn<<<dim3(1, N / 128, S), 256, 0, stream>>>(tT, Tb, P, D, N, K);
    ln_cast_k<<<N / 32, 256, 0, stream>>>(P, gamma, beta, xT, N);
  }
  // sums[e][d] = sum_n hT[e][n] * xT[d][n]
  gemm_tn<<<dim3(E / 128, 1, S), 256, 0, stream>>>(hT, xT, P, E, D, K);
  mm1_k<<<E / 16, 256, 0, stream>>>(P, counts, pm, E * D);
  mm2_k<<<1, 128, 0, stream>>>(pm, out, E / 16);
}

// Round 3
// 824.344 us; speedup vs baseline: 1.1623x; 1.0056x over previous
//
#include <hip/hip_runtime.h>
#include <cstdint>
#include <cstddef>

typedef __attribute__((ext_vector_type(8))) short short8;
typedef __attribute__((ext_vector_type(4))) short short4v;
typedef __attribute__((ext_vector_type(4))) float float4v;
typedef __attribute__((ext_vector_type(4))) int int4v;
typedef unsigned short ushort_t;

__device__ __forceinline__ ushort_t f2bf(float f) {
  unsigned u = __builtin_bit_cast(unsigned, f);
  u = (u + 0x7FFFu + ((u >> 16) & 1u)) >> 16;  // RNE
  return (ushort_t)u;
}
__device__ __forceinline__ float bf2f(ushort_t h) {
  unsigned u = ((unsigned)h) << 16;
  return __builtin_bit_cast(float, u);
}

__device__ __forceinline__ void gld_lds16(const void* g, void* l) {
  __builtin_amdgcn_global_load_lds(
      (const __attribute__((address_space(1))) void*)g,
      (__attribute__((address_space(3))) void*)l, 16, 0, 0);
}

// ---------------------------------------------------------------------------
// Tiled layout: 64x64 bf16 subtiles, row-major within a subtile, subtile
// (i,j) of a [R][C] matrix at elem offset (i*(C/64)+j)*4096. GEMM blocks then
// read 8-16 KiB dense bursts instead of 128-B segments at 16-KiB stride
// (theory: HBM row-buffer/channel locality was capping GEMMs at ~45% BW).
// ---------------------------------------------------------------------------

// TN GEMM, plain-store split-K: P[z][m][n] = sum_{k in slice z} A[m][k]*B[n][k]
// A:[M][K], B:[N][K] bf16; ATILED/BTILED select row-major vs subtiled source.
// Tile 128x128, BK=64. K=8192 -> 128 k-tiles over 12 z-slices (8x11 + 4x10).
__global__ __launch_bounds__(256, 3) void gemm_tn(
    const ushort_t* __restrict__ A, const ushort_t* __restrict__ B,
    float* __restrict__ P, int M, int N, int K, int ATILED, int BTILED) {
  __shared__ ushort_t As[128 * 64];
  __shared__ ushort_t Bs[128 * 64];
  const int tid = threadIdx.x;
  const int lane = tid & 63;
  const int wave = tid >> 6;
  const int wm = (wave & 1) * 64;
  const int wn = (wave >> 1) * 64;
  const int m0 = blockIdx.x * 128;
  const int n0 = blockIdx.y * 128;
  int t0, tl;
  if (blockIdx.z < 8) { t0 = blockIdx.z * 11; tl = 11; }
  else { t0 = 88 + (blockIdx.z - 8) * 10; tl = 10; }
  float* __restrict__ Pc = P + (size_t)blockIdx.z * M * N;

  // Hoisted per-chunk source bases + per-k-tile step (linear in t).
  const char* aP[4];
  const char* bP[4];
  size_t aStep, bStep;
#pragma unroll
  for (int i = 0; i < 4; i++) {
    const int f = i * 4096 + tid * 16;  // flat byte in 16KB LDS tile
    if (ATILED) {
      aP[i] = (const char*)A +
              (((size_t)((m0 >> 6) + (f >> 13)) * (size_t)(K >> 6)) << 13) +
              (f & 8191);
    } else {
      aP[i] = (const char*)A + ((size_t)(m0 + (f >> 7)) * K) * 2 + (f & 127);
    }
    if (BTILED) {
      bP[i] = (const char*)B +
              (((size_t)((n0 >> 6) + (f >> 13)) * (size_t)(K >> 6)) << 13) +
              (f & 8191);
    } else {
      bP[i] = (const char*)B + ((size_t)(n0 + (f >> 7)) * K) * 2 + (f & 127);
    }
  }
  aStep = ATILED ? 8192 : 128;
  bStep = BTILED ? 8192 : 128;

  float4v acc[4][4] = {};

  for (int t = t0; t < t0 + tl; t++) {
#pragma unroll
    for (int i = 0; i < 4; i++) {
      const int f = i * 4096 + tid * 16;
      gld_lds16(aP[i] + (size_t)t * aStep, (char*)As + f);
      gld_lds16(bP[i] + (size_t)t * bStep, (char*)Bs + f);
    }
    __syncthreads();
#pragma unroll
    for (int ks = 0; ks < 64; ks += 32) {
      short8 af[4], bfr[4];
      const int kr = ks + (lane >> 4) * 8;
      const int l15 = lane & 15;
#pragma unroll
      for (int im = 0; im < 4; im++)
        af[im] = *(const short8*)&As[(wm + im * 16 + l15) * 64 + kr];
#pragma unroll
      for (int in = 0; in < 4; in++)
        bfr[in] = *(const short8*)&Bs[(wn + in * 16 + l15) * 64 + kr];
#pragma unroll
      for (int im = 0; im < 4; im++)
#pragma unroll
        for (int in = 0; in < 4; in++)
          acc[im][in] = __builtin_amdgcn_mfma_f32_16x16x32_bf16(
              af[im], bfr[in], acc[im][in], 0, 0, 0);
    }
    __syncthreads();
  }
  // C/D layout: col(n) = lane&15, row(m) = (lane>>4)*4 + reg  [m89/m91]
  const int cn = lane & 15;
  const int cr = (lane >> 4) * 4;
#pragma unroll
  for (int im = 0; im < 4; im++)
#pragma unroll
    for (int in = 0; in < 4; in++)
#pragma unroll
      for (int r = 0; r < 4; r++) {
        int m = wm + im * 16 + cr + r;
        int n = wn + in * 16 + cn;
        Pc[(size_t)(m0 + m) * N + (n0 + n)] = acc[im][in][r];
      }
}

// ---------------------------------------------------------------------------
// NN GEMM: P[z][m][n] = sum_{k in slice z} A[m][k]*B[k][n].
// A:[M][K] row-major; B SUBTILED (B-tile per k-step = 16 KiB contiguous:
// subtiles (i=t, j=n0/64) and (i=t, j=n0/64+1)). LDS granule layout
// [4k][16n] k4-major; fragments via ds_read_b64_tr_b16 (addr bits [6:3]
// select the granule column -> +l15*8 bytes) — verified round 1.
// ---------------------------------------------------------------------------
__global__ __launch_bounds__(256, 3) void gemm_nn(
    const ushort_t* __restrict__ A, const ushort_t* __restrict__ B,
    float* __restrict__ P, int M, int N, int K) {
  __shared__ ushort_t As[128 * 64];
  __shared__ ushort_t Bs[64 * 128];
  const int tid = threadIdx.x;
  const int lane = tid & 63;
  const int wave = tid >> 6;
  const int wm = (wave & 1) * 64;
  const int wn = (wave >> 1) * 64;
  const int m0 = blockIdx.x * 128;
  const int n0 = blockIdx.y * 128;
  int t0, tl;
  if (blockIdx.z < 8) { t0 = blockIdx.z * 11; tl = 11; }
  else { t0 = 88 + (blockIdx.z - 8) * 10; tl = 10; }
  float* __restrict__ Pc = P + (size_t)blockIdx.z * M * N;

  // B-staging: 16B chunk c -> (k row, col) of the tile; source offset within
  // the 16-KiB two-subtile window.
  const char* aP[4];
  const char* bP[4];
#pragma unroll
  for (int i = 0; i < 4; i++) {
    const int c = i * 256 + tid;
    const int f = i * 4096 + tid * 16;
    const int brow = ((c >> 6) << 2) | ((c >> 1) & 3);        // k in 0..63
    const int bcol = (((c >> 3) & 7) << 4) | ((c & 1) << 3);  // n in 0..127
    const int bsrc = (bcol & 64 ? 8192 : 0) + brow * 128 + (bcol & 63) * 2;
    bP[i] = (const char*)B + ((size_t)(n0 >> 6) << 13) + bsrc;
    aP[i] = (const char*)A + ((size_t)(m0 + (f >> 7)) * K) * 2 + (f & 127);
  }
  const size_t bStep = (size_t)(N >> 6) << 13;  // next k-tile = next subtile row

  const int l15 = lane & 15;
  const int hi = lane >> 4;
  const unsigned BsB =
      (unsigned)(uintptr_t)(__attribute__((address_space(3))) void*)Bs;
  const unsigned trb = BsB + (unsigned)(hi * 2048) + (unsigned)(l15 * 8);

  float4v acc[4][4] = {};

  for (int t = t0; t < t0 + tl; t++) {
#pragma unroll
    for (int i = 0; i < 4; i++) {
      const int f = i * 4096 + tid * 16;
      gld_lds16(aP[i] + (size_t)t * 128, (char*)As + f);
      gld_lds16(bP[i] + (size_t)t * bStep, (char*)Bs + f);
    }
    __syncthreads();
#pragma unroll
    for (int ks = 0; ks < 64; ks += 32) {
      short8 af[4];
      const int kr = ks + hi * 8;
#pragma unroll
      for (int im = 0; im < 4; im++)
        af[im] = *(const short8*)&As[(wm + im * 16 + l15) * 64 + kr];
      short4v r0[4], r1[4];
      const unsigned tb = trb + (unsigned)((ks >> 2) * 1024) + (unsigned)(wn * 8);
#pragma unroll
      for (int in = 0; in < 4; in++) {
        asm volatile(
            "ds_read_b64_tr_b16 %0, %2\n\t"
            "ds_read_b64_tr_b16 %1, %2 offset:1024"
            : "=&v"(r0[in]), "=&v"(r1[in])
            : "v"(tb + (unsigned)(in * 128)));
      }
      asm volatile("s_waitcnt lgkmcnt(0)" ::: "memory");
      __builtin_amdgcn_sched_barrier(0);
#pragma unroll
      for (int im = 0; im < 4; im++)
#pragma unroll
        for (int in = 0; in < 4; in++) {
          short8 bf8 = __builtin_shufflevector(r0[in], r1[in],
                                               0, 1, 2, 3, 4, 5, 6, 7);
          acc[im][in] = __builtin_amdgcn_mfma_f32_16x16x32_bf16(
              af[im], bf8, acc[im][in], 0, 0, 0);
        }
    }
    __syncthreads();
  }
  const int cn = lane & 15;
  const int cr = (lane >> 4) * 4;
#pragma unroll
  for (int im = 0; im < 4; im++)
#pragma unroll
    for (int in = 0; in < 4; in++)
#pragma unroll
      for (int r = 0; r < 4; r++) {
        int m = wm + im * 16 + cr + r;
        int n = wn + in * 16 + cn;
        Pc[(size_t)(m0 + m) * N + (n0 + n)] = acc[im][in][r];
      }
}

// ---------------------------------------------------------------------------
// fp32 [8192][8192] -> bf16 subtiled (fused cast+repack). Block = 32 rows x
// 512 cols; reads 2-KiB row segments, writes 8 half-subtiles of 4 KiB.
// ---------------------------------------------------------------------------
__global__ __launch_bounds__(256) void repack_T_k(
    const float* __restrict__ src, ushort_t* __restrict__ dst) {
  __shared__ ushort_t tile[32][520];
  const int bx = blockIdx.x;  // 16 strips of 512 cols
  const int by = blockIdx.y;  // 256 strips of 32 rows
  const int t = threadIdx.x;
  const int r = t >> 3, cs = (t & 7) * 64;
  const float* s = src + (size_t)(by * 32 + r) * 8192 + bx * 512 + cs;
#pragma unroll
  for (int j = 0; j < 64; j += 4) {
    float4v v = *(const float4v*)(s + j);
    short4v o;
    o.x = (short)f2bf(v.x); o.y = (short)f2bf(v.y);
    o.z = (short)f2bf(v.z); o.w = (short)f2bf(v.w);
    *(short4v*)&tile[r][cs + j] = o;
  }
  __syncthreads();
  const int q = t & 7;
  ushort_t* d = dst + ((size_t)(by >> 1) * 128 + bx * 8) * 4096 +
                (size_t)(by & 1) * 2048 + r * 64 + q * 8;
#pragma unroll
  for (int jj = 0; jj < 8; jj++)
    *(short8*)(d + (size_t)jj * 4096) = *(const short8*)&tile[r][jj * 64 + q * 8];
}

// ---------------------------------------------------------------------------
// fp32 [R][C] -> bf16 transposed [C][R] (x0 only; small).
// ---------------------------------------------------------------------------
__global__ __launch_bounds__(256) void dualcast_f32_k(
    const float* __restrict__ src, ushort_t* __restrict__ dstN,
    ushort_t* __restrict__ dstT, int R, int C) {
  __shared__ float tile[64][65];
  const int c0 = blockIdx.x * 64, r0 = blockIdx.y * 64;
  const int tr = threadIdx.x >> 2, cs = (threadIdx.x & 3) * 16;
  const float* s = src + (size_t)(r0 + tr) * C + c0 + cs;
  float v[16];
#pragma unroll
  for (int j = 0; j < 16; j += 4) {
    float4v t4 = *(const float4v*)(s + j);
    v[j] = t4.x; v[j + 1] = t4.y; v[j + 2] = t4.z; v[j + 3] = t4.w;
  }
  if (dstN) {
    ushort_t o[16];
#pragma unroll
    for (int j = 0; j < 16; j++) o[j] = f2bf(v[j]);
    ushort_t* d = dstN + (size_t)(r0 + tr) * C + c0 + cs;
    *(short8*)d = *(const short8*)&o[0];
    *(short8*)(d + 8) = *(const short8*)&o[8];
  }
#pragma unroll
  for (int j = 0; j < 16; j++) tile[tr][cs + j] = v[j];
  __syncthreads();
  const int tc = threadIdx.x >> 2, rs = (threadIdx.x & 3) * 16;
  ushort_t o[16];
#pragma unroll
  for (int j = 0; j < 16; j++) o[j] = f2bf(tile[rs + j][tc]);
  ushort_t* d = dstT + (size_t)(c0 + tc) * R + r0 + rs;
  *(short8*)d = *(const short8*)&o[0];
  *(short8*)(d + 8) = *(const short8*)&o[8];
}

// int32 h[R=N][C=E] -> bf16 (x>0) hT SUBTILED ([E/64][N/64] subtiles) +
// per-block column partial sums for counts.
__global__ __launch_bounds__(256) void tcast_i32_k(
    const int* __restrict__ src, ushort_t* __restrict__ dstT,
    float* __restrict__ partial, int R, int C) {
  __shared__ float tile[64][65];
  const int c0 = blockIdx.x * 64, r0 = blockIdx.y * 64;
  const int tr = threadIdx.x >> 2, cs = (threadIdx.x & 3) * 16;
  const int* s = src + (size_t)(r0 + tr) * C + c0 + cs;
#pragma unroll
  for (int j = 0; j < 16; j += 4) {
    int4v t4 = *(const int4v*)(s + j);
    tile[tr][cs + j] = t4.x > 0 ? 1.f : 0.f;
    tile[tr][cs + j + 1] = t4.y > 0 ? 1.f : 0.f;
    tile[tr][cs + j + 2] = t4.z > 0 ? 1.f : 0.f;
    tile[tr][cs + j + 3] = t4.w > 0 ? 1.f : 0.f;
  }
  __syncthreads();
  const int tc = threadIdx.x >> 2, rs = (threadIdx.x & 3) * 16;
  ushort_t o[16];
#pragma unroll
  for (int j = 0; j < 16; j++) o[j] = f2bf(tile[rs + j][tc]);
  // subtile (i = e-tile = c0/64, j = n-tile = r0/64); within: e*64 + n
  ushort_t* d = dstT + (((size_t)(c0 >> 6) * (size_t)(R >> 6) + (r0 >> 6)) << 12) +
                tc * 64 + rs;
  *(short8*)d = *(const short8*)&o[0];
  *(short8*)(d + 8) = *(const short8*)&o[8];
  if (threadIdx.x < 64) {
    float sum = 0.f;
#pragma unroll
    for (int r = 0; r < 64; r++) sum += tile[r][threadIdx.x];
    partial[(size_t)(r0 >> 6) * C + c0 + threadIdx.x] = sum;
  }
}

// counts[e] = sum over 128 row-tiles of partial[rt][e]
__global__ __launch_bounds__(256) void counts2_k(
    const float* __restrict__ partial, float* __restrict__ counts, int E) {
  const int e = blockIdx.x * 256 + threadIdx.x;
  float s = 0.f;
  for (int r = 0; r < 128; r++) s += partial[(size_t)r * E + e];
  counts[e] = s;
}

// out_bf16[i] = bf16( sum_s P[s][i] ), S=12 slices
__global__ __launch_bounds__(256) void cast_k(
    const float* __restrict__ P, ushort_t* __restrict__ out, int MN) {
  const int i = (blockIdx.x * 256 + threadIdx.x) * 8;
  float4v a = {0.f, 0.f, 0.f, 0.f}, b = {0.f, 0.f, 0.f, 0.f};
  for (int sp = 0; sp < 12; sp++) {
    a += *(const float4v*)&P[(size_t)sp * MN + i];
    b += *(const float4v*)&P[(size_t)sp * MN + i + 4];
  }
  ushort_t o[8];
  o[0] = f2bf(a.x); o[1] = f2bf(a.y); o[2] = f2bf(a.z); o[3] = f2bf(a.w);
  o[4] = f2bf(b.x); o[5] = f2bf(b.y); o[6] = f2bf(b.z); o[7] = f2bf(b.w);
  *(short8*)&out[i] = *(const short8*)o;
}

// P[s][d][m]: sum 12 slices, LayerNorm over d per column m, write xT[d][m] bf16.
__global__ __launch_bounds__(256) void ln_cast_k(
    const float* __restrict__ P, const float* __restrict__ gamma,
    const float* __restrict__ beta, ushort_t* __restrict__ xT, int Ncols) {
  __shared__ float ssum[8][32], ssq[8][32];
  const int c = threadIdx.x & 31;
  const int q = threadIdx.x >> 5;
  const int m = blockIdx.x * 32 + c;
  const size_t DN = (size_t)128 * Ncols;
  float vloc[16];
  float s = 0.f, sq = 0.f;
#pragma unroll
  for (int j = 0; j < 16; j++) {
    const int d = q * 16 + j;
    float v = 0.f;
    for (int sp = 0; sp < 12; sp++)
      v += P[(size_t)sp * DN + (size_t)d * Ncols + m];
    vloc[j] = v; s += v; sq += v * v;
  }
  ssum[q][c] = s;
  ssq[q][c] = sq;
  __syncthreads();
  float S = 0.f, SQ = 0.f;
#pragma unroll
  for (int r = 0; r < 8; r++) { S += ssum[r][c]; SQ += ssq[r][c]; }
  const float mean = S * (1.f / 128.f);
  const float var = SQ * (1.f / 128.f) - mean * mean;
  const float inv = rsqrtf(var + 1e-5f);
#pragma unroll
  for (int j = 0; j < 16; j++) {
    const int d = q * 16 + j;
    xT[(size_t)d * Ncols + m] = f2bf((vloc[j] - mean) * inv * gamma[d] + beta[d]);
  }
}

// P[s][e][128]: sum 12 slices, divide by counts[e], partial max over 16 e/block
__global__ __launch_bounds__(256) void mm1_k(
    const float* __restrict__ P, const float* __restrict__ counts,
    float* __restrict__ pm, int EMN) {
  __shared__ float4v red[8][32];
  const int el = threadIdx.x >> 5;
  const int l32 = threadIdx.x & 31;
  const int e0 = blockIdx.x * 16;
  float4v vmax = {-3.4e38f, -3.4e38f, -3.4e38f, -3.4e38f};
  for (int ee = el; ee < 16; ee += 8) {
    const int e = e0 + ee;
    float4v s = {0.f, 0.f, 0.f, 0.f};
    for (int sp = 0; sp < 12; sp++)
      s += *(const float4v*)&P[(size_t)sp * EMN + (size_t)e * 128 + l32 * 4];
    const float inv = 1.f / counts[e];
    s *= inv;
    vmax.x = fmaxf(vmax.x, s.x); vmax.y = fmaxf(vmax.y, s.y);
    vmax.z = fmaxf(vmax.z, s.z); vmax.w = fmaxf(vmax.w, s.w);
  }
  red[el][l32] = vmax;
  __syncthreads();
  if (el == 0) {
    float4v m = red[0][l32];
#pragma unroll
    for (int r = 1; r < 8; r++) {
      float4v t = red[r][l32];
      m.x = fmaxf(m.x, t.x); m.y = fmaxf(m.y, t.y);
      m.z = fmaxf(m.z, t.z); m.w = fmaxf(m.w, t.w);
    }
    *(float4v*)&pm[(size_t)blockIdx.x * 128 + l32 * 4] = m;
  }
}

__global__ __launch_bounds__(128) void mm2_k(
    const float* __restrict__ pm, float* __restrict__ out, int B) {
  const int d = threadIdx.x;
  float v = -3.4e38f;
  for (int b = 0; b < B; b++) v = fmaxf(v, pm[b * 128 + d]);
  out[d] = v;
}

// ---------------------------------------------------------------------------
extern "C" void kernel_launch(void* const* d_in, const int* in_sizes, int n_in,
                              void* d_out, int out_size, void* d_ws,
                              size_t ws_size, hipStream_t stream) {
  const float* x0 = (const float*)d_in[0];
  const float* T = (const float*)d_in[1];
  const float* gamma = (const float*)d_in[2];
  const float* beta = (const float*)d_in[3];
  const int* h = (const int*)d_in[4];
  float* out = (float*)d_out;

  const int N = 8192, E = 4096, D = 128, K = 8192, S = 12;

  char* ws = (char*)d_ws;
  size_t off = 0;
  auto alloc = [&](size_t bytes) {
    char* p = ws + off;
    off += (bytes + 255) & ~(size_t)255;
    return p;
  };
  ushort_t* Tb = (ushort_t*)alloc((size_t)N * N * 2);  // T bf16 SUBTILED
  ushort_t* hT = (ushort_t*)alloc((size_t)E * N * 2);  // h^T bf16 SUBTILED
  ushort_t* xT = (ushort_t*)alloc((size_t)D * N * 2);  // x^T bf16 [128][8192]
  ushort_t* tT = (ushort_t*)alloc((size_t)D * N * 2);  // t^T bf16 [128][8192]
  float* P = (float*)alloc((size_t)S * D * N * 4);     // split-K partials 48MB
  float* counts = (float*)alloc((size_t)E * 4);
  float* partial = (float*)alloc((size_t)(N / 64) * E * 4);  // 2MB count partials
  float* pm = (float*)alloc((size_t)256 * D * 4);
  (void)ws_size;

  repack_T_k<<<dim3(16, 256), 256, 0, stream>>>(T, Tb);
  dualcast_f32_k<<<dim3(D / 64, N / 64), 256, 0, stream>>>(x0, nullptr, xT, N, D);
  tcast_i32_k<<<dim3(E / 64, N / 64), 256, 0, stream>>>(h, hT, partial, N, E);
  counts2_k<<<E / 256, 256, 0, stream>>>(partial, counts, E);

  for (int layer = 0; layer < 3; layer++) {
    // tT[d][n] = sum_k xT[d][k] * T[n][k]  (TN; B = Tb tiled, i=n/64, j=t)
    gemm_tn<<<dim3(1, N / 128, S), 256, 0, stream>>>(xT, Tb, P, D, N, K, 0, 1);
    cast_k<<<D * N / (256 * 8), 256, 0, stream>>>(P, tT, D * N);
    // x'T[d][m] = sum_k tT[d][k] * T[k][m]  (NN; B = Tb tiled, i=t, j=m/64)
    gemm_nn<<<dim3(1, N / 128, S), 256, 0, stream>>>(tT, Tb, P, D, N, K);
    ln_cast_k<<<N / 32, 256, 0, stream>>>(P, gamma, beta, xT, N);
  }
  // sums[e][d] = sum_n hT[e][n] * xT[d][n]  (TN; A = hT tiled, B = xT rowmajor)
  gemm_tn<<<dim3(E / 128, 1, S), 256, 0, stream>>>(hT, xT, P, E, D, K, 1, 0);
  mm1_k<<<E / 16, 256, 0, stream>>>(P, counts, pm, E * D);
  mm2_k<<<1, 128, 0, stream>>>(pm, out, E / 16);
}